// Round 3
// baseline (138.351 us; speedup 1.0000x reference)
//
#include <hip/hip_runtime.h>

// Problem dims (fixed by reference setup_inputs)
#define B_  4
#define C_  3
#define S_  5
#define M_  18
#define HW4 11264              // 256*176/4 float4s per plane/channel
#define G_  6                  // m-planes per block (one per wave)
#define NGRP (M_/G_)           // 3 wave-groups per (b,s)
#define SPLIT 8                // chunks per plane
#define CHUNK4 (HW4/SPLIT)     // 1408 float4s per chunk
#define WITER (CHUNK4/64)      // 22 iterations per wave
#define TPB (G_*64)            // 384 threads = 6 waves
#define NPLANE (B_*S_*M_)      // 360
#define NBLK (B_*S_*NGRP*SPLIT) // 480 blocks
#define PART_OFF 64            // floats; counter lives at ws[0]

// Fused kernel: each wave accumulates 16 raw weighted moments for ONE
// (b,s,m) plane over one chunk; all 6 waves in a block share the same X/Y
// addresses (L1 broadcast). Last block (atomic ticket) runs the epilogue.
// Partial layout per (plane,chunk): [0]=msum, [1+c*5+{wx,wy,wxx,wyy,wxy}]
__global__ __launch_bounds__(TPB) void fused_kernel(
    const float4* __restrict__ X, const float4* __restrict__ Y,
    const float4* __restrict__ Mk, float* __restrict__ ws,
    float* __restrict__ out) {
  float* part = ws + PART_OFF;
  unsigned int* cnt = (unsigned int*)ws;

  int bid   = blockIdx.x;          // [0, NBLK)
  int g     = bid / SPLIT;         // [0, 60): (b,s,gm)
  int chunk = bid - g * SPLIT;
  int bs    = g / NGRP;            // b*S_ + s
  int gm    = g - bs * NGRP;
  int b     = bs / S_;
  int wv    = threadIdx.x >> 6;    // wave id = which m within group
  int lane  = threadIdx.x & 63;
  int plane = bs * M_ + gm * G_ + wv;

  const float4* mp = Mk + (size_t)plane * HW4;
  const float4* xp = X  + (size_t)b * (C_ * HW4);
  const float4* yp = Y  + (size_t)b * (C_ * HW4);

  int base = chunk * CHUNK4 + lane;

  float v[16];
#pragma unroll
  for (int j = 0; j < 16; ++j) v[j] = 0.f;

#pragma unroll
  for (int it = 0; it < WITER; ++it) {
    int i = base + it * 64;
    float4 w = mp[i];
    float4 xv[C_], yv[C_];
#pragma unroll
    for (int c = 0; c < C_; ++c) { xv[c] = xp[c * HW4 + i]; yv[c] = yp[c * HW4 + i]; }

    float w4[4] = { w.x, w.y, w.z, w.w };
    float x4[C_][4] = { {xv[0].x, xv[0].y, xv[0].z, xv[0].w},
                        {xv[1].x, xv[1].y, xv[1].z, xv[1].w},
                        {xv[2].x, xv[2].y, xv[2].z, xv[2].w} };
    float y4[C_][4] = { {yv[0].x, yv[0].y, yv[0].z, yv[0].w},
                        {yv[1].x, yv[1].y, yv[1].z, yv[1].w},
                        {yv[2].x, yv[2].y, yv[2].z, yv[2].w} };
#pragma unroll
    for (int k = 0; k < 4; ++k) {
      float wk = w4[k];
      v[0] += wk;
#pragma unroll
      for (int c = 0; c < C_; ++c) {
        float xs = fmaf(x4[c][k], 0.5f, 0.5f);
        float ys = fmaf(y4[c][k], 0.5f, 0.5f);
        float wx = wk * xs, wy = wk * ys;
        v[1 + c*5 + 0] = fmaf(wk, xs, v[1 + c*5 + 0]);
        v[1 + c*5 + 1] = fmaf(wk, ys, v[1 + c*5 + 1]);
        v[1 + c*5 + 2] = fmaf(wx, xs, v[1 + c*5 + 2]);
        v[1 + c*5 + 3] = fmaf(wy, ys, v[1 + c*5 + 3]);
        v[1 + c*5 + 4] = fmaf(wx, ys, v[1 + c*5 + 4]);
      }
    }
  }

  // wave-64 butterfly over the 16 per-plane values (no cross-wave reduce needed)
#pragma unroll
  for (int off = 32; off > 0; off >>= 1) {
#pragma unroll
    for (int j = 0; j < 16; ++j) v[j] += __shfl_xor(v[j], off);
  }

  if (lane == 0) {
    float4* dst = (float4*)(part + (size_t)(plane * SPLIT + chunk) * 16);
    dst[0] = make_float4(v[0],  v[1],  v[2],  v[3]);
    dst[1] = make_float4(v[4],  v[5],  v[6],  v[7]);
    dst[2] = make_float4(v[8],  v[9],  v[10], v[11]);
    dst[3] = make_float4(v[12], v[13], v[14], v[15]);
  }

  // ---- last-block ticket ----
  __shared__ unsigned int isLast;
  __syncthreads();                 // all waves' partial stores done (vmcnt drained)
  if (threadIdx.x == 0) {
    __threadfence();               // agent-scope release (cross-XCD L2 writeback)
    unsigned int ret = atomicAdd(cnt, 1u);
    isLast = (ret == (unsigned int)(NBLK - 1)) ? 1u : 0u;
  }
  __syncthreads();
  if (!isLast) return;
  __threadfence();                 // agent-scope acquire (invalidate stale lines)

  // ---- epilogue (one block, deterministic order) ----
  __shared__ float csS[NPLANE], ssS[NPLANE];
  __shared__ double csb[B_*S_], ssb[B_*S_];
  int t = threadIdx.x;

  if (t < NPLANE) {
    double s[16];
#pragma unroll
    for (int j = 0; j < 16; ++j) s[j] = 0.0;
    for (int ch = 0; ch < SPLIT; ++ch) {
      const float* p = part + (size_t)(t * SPLIT + ch) * 16;
#pragma unroll
      for (int j = 0; j < 16; ++j) s[j] += (double)p[j];
    }
    const double C1d = 1e-4, C2d = 9e-4;
    double inv = 1.0 / (s[0] + 1e-6);
    double csAcc = 0.0, ssAcc = 0.0;
#pragma unroll
    for (int c = 0; c < C_; ++c) {
      double mu1  = s[1 + c*5 + 0] * inv;
      double mu2  = s[1 + c*5 + 1] * inv;
      double mu11 = s[1 + c*5 + 2] * inv;
      double mu22 = s[1 + c*5 + 3] * inv;
      double mu12 = s[1 + c*5 + 4] * inv;
      double m1s = mu1*mu1, m2s = mu2*mu2, m12 = mu1*mu2;
      double sig1  = mu11 - m1s;
      double sig2  = mu22 - m2s;
      double sig12 = mu12 - m12;
      double cs   = (2.0*sig12 + C2d) / (sig1 + sig2 + C2d);
      double ssim = (2.0*m12 + C1d) / (m1s + m2s + C1d) * cs;
      if (cs   < 0.0) cs   = 0.0;
      if (ssim < 0.0) ssim = 0.0;
      csAcc += cs; ssAcc += ssim;
    }
    csS[t] = (float)csAcc;
    ssS[t] = (float)ssAcc;
  }
  __syncthreads();

  if (t < B_*S_) {  // t = b*S_ + s
    double cb = 0.0, sb = 0.0;
    for (int m = 0; m < M_; ++m) { cb += (double)csS[t*M_ + m]; sb += (double)ssS[t*M_ + m]; }
    csb[t] = cb / (double)(M_*C_);
    ssb[t] = sb / (double)(M_*C_);
  }
  __syncthreads();

  if (t == 0) {
    double acc = 0.0;
    for (int bb = 0; bb < B_; ++bb) {
      double p = ssb[bb*S_ + (S_-1)];
      for (int s = 0; s < S_-1; ++s) p *= csb[bb*S_ + s];
      acc += p;
    }
    out[0] = (float)(acc / (double)B_);
  }
}

extern "C" void kernel_launch(void* const* d_in, const int* in_sizes, int n_in,
                              void* d_out, int out_size, void* d_ws, size_t ws_size,
                              hipStream_t stream) {
  (void)in_sizes; (void)n_in; (void)out_size; (void)ws_size;
  const float4* X  = (const float4*)d_in[0];
  const float4* Y  = (const float4*)d_in[1];
  const float4* Mk = (const float4*)d_in[2];
  float* ws  = (float*)d_ws;   // [0]=counter, [64...]=partials (184 KB)
  float* out = (float*)d_out;

  // zero the ticket counter (ws is re-poisoned to 0xAA before every launch)
  hipMemsetAsync(d_ws, 0, 4, stream);
  hipLaunchKernelGGL(fused_kernel, dim3(NBLK), dim3(TPB), 0, stream,
                     X, Y, Mk, ws, out);
}

// Round 4
// 119.679 us; speedup vs baseline: 1.1560x; 1.1560x over previous
//
#include <hip/hip_runtime.h>

// Problem dims (fixed by reference setup_inputs)
#define B_  4
#define C_  3
#define S_  5
#define M_  18
#define HW4 11264            // 256*176/4 float4s per plane/channel
#define SPLIT 11             // chunks per (b,s,m) plane  -> 3960 blocks
#define TPB 256
#define CHUNK4 (HW4/SPLIT)   // 1024 float4s per block
#define ITERS (CHUNK4/TPB)   // 4 iterations per thread
#define NPLANE (B_*S_*M_)    // 360

// Kernel A: per-(plane,chunk) partial sums of the 16 weighted moments.
// 3960 blocks x 4 waves = 62 waves/CU supplied -> resident capped by VGPR,
// maximizing latency hiding (R3 counters: latency-bound, occupancy-starved).
// Layout per (plane,chunk): [0]=msum, [1+c*5+{wx,wy,wxx,wyy,wxy}]
__global__ __launch_bounds__(TPB) void moments_kernel(
    const float4* __restrict__ X, const float4* __restrict__ Y,
    const float4* __restrict__ Mk, float* __restrict__ part) {
  int bid   = blockIdx.x;           // [0, NPLANE*SPLIT)
  int plane = bid / SPLIT;          // (b,s,m)
  int chunk = bid - plane * SPLIT;
  int b     = plane / (S_ * M_);

  const float4* mp = Mk + (size_t)plane * HW4;
  const float4* xp = X  + (size_t)b * (C_ * HW4);
  const float4* yp = Y  + (size_t)b * (C_ * HW4);

  int base = chunk * CHUNK4 + (int)threadIdx.x;

  float v[16];
#pragma unroll
  for (int j = 0; j < 16; ++j) v[j] = 0.f;

#pragma unroll
  for (int it = 0; it < ITERS; ++it) {
    int i = base + it * TPB;
    float4 w = mp[i];                       // HBM stream — issue first
    float4 xv[C_], yv[C_];
#pragma unroll
    for (int c = 0; c < C_; ++c) { xv[c] = xp[c * HW4 + i]; yv[c] = yp[c * HW4 + i]; }

    float w4[4]     = { w.x, w.y, w.z, w.w };
    float x4[C_][4] = { {xv[0].x, xv[0].y, xv[0].z, xv[0].w},
                        {xv[1].x, xv[1].y, xv[1].z, xv[1].w},
                        {xv[2].x, xv[2].y, xv[2].z, xv[2].w} };
    float y4[C_][4] = { {yv[0].x, yv[0].y, yv[0].z, yv[0].w},
                        {yv[1].x, yv[1].y, yv[1].z, yv[1].w},
                        {yv[2].x, yv[2].y, yv[2].z, yv[2].w} };
#pragma unroll
    for (int k = 0; k < 4; ++k) {
      float wk = w4[k];
      v[0] += wk;
#pragma unroll
      for (int c = 0; c < C_; ++c) {
        float xs = fmaf(x4[c][k], 0.5f, 0.5f);
        float ys = fmaf(y4[c][k], 0.5f, 0.5f);
        float wx = wk * xs, wy = wk * ys;
        v[1 + c*5 + 0] = fmaf(wk, xs, v[1 + c*5 + 0]);
        v[1 + c*5 + 1] = fmaf(wk, ys, v[1 + c*5 + 1]);
        v[1 + c*5 + 2] = fmaf(wx, xs, v[1 + c*5 + 2]);
        v[1 + c*5 + 3] = fmaf(wy, ys, v[1 + c*5 + 3]);
        v[1 + c*5 + 4] = fmaf(wx, ys, v[1 + c*5 + 4]);
      }
    }
  }

  // wave-64 butterfly reduce all 16 values
#pragma unroll
  for (int off = 32; off > 0; off >>= 1) {
#pragma unroll
    for (int j = 0; j < 16; ++j) v[j] += __shfl_xor(v[j], off);
  }

  __shared__ float red[TPB/64][16];
  int lane = threadIdx.x & 63;
  int wv   = threadIdx.x >> 6;
  if (lane == 0) {
#pragma unroll
    for (int j = 0; j < 16; ++j) red[wv][j] = v[j];
  }
  __syncthreads();
  if (threadIdx.x < 16) {
    float s = (red[0][threadIdx.x] + red[1][threadIdx.x]) +
              (red[2][threadIdx.x] + red[3][threadIdx.x]);
    part[(size_t)bid * 16 + threadIdx.x] = s;
  }
}

// Kernel B: tiny epilogue. One block.
__global__ __launch_bounds__(384) void finalize_kernel(
    const float* __restrict__ part, float* __restrict__ out) {
  __shared__ float csS[NPLANE], ssS[NPLANE];
  __shared__ double csb[B_*S_], ssb[B_*S_];
  int t = threadIdx.x;

  if (t < NPLANE) {
    double s[16];
#pragma unroll
    for (int j = 0; j < 16; ++j) s[j] = 0.0;
    for (int ch = 0; ch < SPLIT; ++ch) {
      const float* p = part + (size_t)(t * SPLIT + ch) * 16;
#pragma unroll
      for (int j = 0; j < 16; ++j) s[j] += (double)p[j];
    }
    const double C1d = 1e-4, C2d = 9e-4;
    double inv = 1.0 / (s[0] + 1e-6);
    double csAcc = 0.0, ssAcc = 0.0;
#pragma unroll
    for (int c = 0; c < C_; ++c) {
      double mu1  = s[1 + c*5 + 0] * inv;
      double mu2  = s[1 + c*5 + 1] * inv;
      double mu11 = s[1 + c*5 + 2] * inv;
      double mu22 = s[1 + c*5 + 3] * inv;
      double mu12 = s[1 + c*5 + 4] * inv;
      double m1s = mu1*mu1, m2s = mu2*mu2, m12 = mu1*mu2;
      double sig1  = mu11 - m1s;
      double sig2  = mu22 - m2s;
      double sig12 = mu12 - m12;
      double cs   = (2.0*sig12 + C2d) / (sig1 + sig2 + C2d);
      double ssim = (2.0*m12 + C1d) / (m1s + m2s + C1d) * cs;
      if (cs   < 0.0) cs   = 0.0;
      if (ssim < 0.0) ssim = 0.0;
      csAcc += cs; ssAcc += ssim;
    }
    csS[t] = (float)csAcc;
    ssS[t] = (float)ssAcc;
  }
  __syncthreads();

  if (t < B_*S_) {  // t = b*S_ + s
    double cb = 0.0, sb = 0.0;
    for (int m = 0; m < M_; ++m) { cb += (double)csS[t*M_ + m]; sb += (double)ssS[t*M_ + m]; }
    csb[t] = cb / (double)(M_*C_);
    ssb[t] = sb / (double)(M_*C_);
  }
  __syncthreads();

  if (t == 0) {
    double acc = 0.0;
    for (int b = 0; b < B_; ++b) {
      double p = ssb[b*S_ + (S_-1)];
      for (int s = 0; s < S_-1; ++s) p *= csb[b*S_ + s];
      acc += p;
    }
    out[0] = (float)(acc / (double)B_);
  }
}

extern "C" void kernel_launch(void* const* d_in, const int* in_sizes, int n_in,
                              void* d_out, int out_size, void* d_ws, size_t ws_size,
                              hipStream_t stream) {
  (void)in_sizes; (void)n_in; (void)out_size; (void)ws_size;
  const float4* X  = (const float4*)d_in[0];
  const float4* Y  = (const float4*)d_in[1];
  const float4* Mk = (const float4*)d_in[2];
  float* part = (float*)d_ws;        // NPLANE*SPLIT*16 floats = 253 KB
  float* out  = (float*)d_out;

  hipLaunchKernelGGL(moments_kernel, dim3(NPLANE*SPLIT), dim3(TPB), 0, stream,
                     X, Y, Mk, part);
  hipLaunchKernelGGL(finalize_kernel, dim3(1), dim3(384), 0, stream, part, out);
}